// Round 8
// baseline (447.744 us; speedup 1.0000x reference)
//
#include <hip/hip_runtime.h>
#include <hip/hip_bf16.h>

#define D_EMB 128
#define T_HIST 200
#define T_PAD 208
#define NG 6400      // f32x4 granules per batch row
#define ITERS 64
#define NBLK 256

typedef float f32x4 __attribute__((ext_vector_type(4)));
typedef short bf16x8 __attribute__((ext_vector_type(8)));

__device__ __forceinline__ short f2bf(float f) {
    unsigned u = __builtin_bit_cast(unsigned, f);
    u += 0x7fffu + ((u >> 16) & 1u);
    return (short)(u >> 16);
}

// Raw workgroup barrier: publishes all LDS traffic (lgkmcnt(0)) but does NOT
// drain outstanding global register loads (vmcnt) like __syncthreads does.
// sched_barrier(0) fences compiler motion across it (rule #18).
__device__ __forceinline__ void wg_barrier() {
    asm volatile("s_waitcnt lgkmcnt(0)" ::: "memory");
    __builtin_amdgcn_s_barrier();
    __builtin_amdgcn_sched_barrier(0);
}

// proven DPP 16-lane-group sum (rounds 2 vs 3 bit-identical vs shfl)
__device__ __forceinline__ float dpp_reduce16(float x) {
    int v = __builtin_bit_cast(int, x);
    x += __builtin_bit_cast(float, __builtin_amdgcn_update_dpp(0, v, 0xB1, 0xF, 0xF, true));
    v = __builtin_bit_cast(int, x);
    x += __builtin_bit_cast(float, __builtin_amdgcn_update_dpp(0, v, 0x4E, 0xF, 0xF, true));
    v = __builtin_bit_cast(int, x);
    x += __builtin_bit_cast(float, __builtin_amdgcn_update_dpp(0, v, 0x141, 0xF, 0xF, true));
    v = __builtin_bit_cast(int, x);
    x += __builtin_bit_cast(float, __builtin_amdgcn_update_dpp(0, v, 0x140, 0xF, 0xF, true));
    return x;
}

// f32x4 granule -> 4 packed RNE bf16 (8B), via HW packed convert
__device__ __forceinline__ uint2 cvt_granule(f32x4 v) {
    uint2 r;
    asm("v_cvt_pk_bf16_f32 %0, %1, %2" : "=v"(r.x) : "v"(v[0]), "v"(v[1]));
    asm("v_cvt_pk_bf16_f32 %0, %1, %2" : "=v"(r.y) : "v"(v[2]), "v"(v[3]));
    return r;
}

__global__ void pack_w_kernel(const float* __restrict__ W, short* __restrict__ wfrag) {
    int tid = blockIdx.x * blockDim.x + threadIdx.x;
    int fragid = tid >> 6;
    int lane = tid & 63;
    int ks = fragid >> 3;
    int nt = fragid & 7;
    int n = nt * 16 + (lane & 15);
    int k0 = ks * 32 + (lane >> 4) * 8;
    bf16x8 r;
#pragma unroll
    for (int j = 0; j < 8; ++j) r[j] = f2bf(W[(k0 + j) * D_EMB + n]);
    ((bf16x8*)wfrag)[fragid * 64 + lane] = r;
}

__global__ void tw_kernel(const float* __restrict__ target, const float* __restrict__ W,
                          const float* __restrict__ bias, float* __restrict__ TW) {
    int e = threadIdx.x;
    int b0 = blockIdx.x * 8;
    float bv = bias[e];
    float acc[8];
#pragma unroll
    for (int i = 0; i < 8; ++i) acc[i] = bv;
    for (int d = 0; d < D_EMB; ++d) {
        float wv = W[d * D_EMB + e];
#pragma unroll
        for (int i = 0; i < 8; ++i)
            acc[i] = fmaf(target[(size_t)(b0 + i) * D_EMB + d], wv, acc[i]);
    }
#pragma unroll
    for (int i = 0; i < 8; ++i) TW[(size_t)(b0 + i) * D_EMB + e] = acc[i];
}

// Round-7 kernel with ONE structural change: all __syncthreads() replaced by
// raw lgkmcnt(0)+s_barrier (wg_barrier). Global loads into registers now stay
// in flight across barriers; the compiler's own counted vmcnt before the
// commit's register uses (issued a full body earlier) is the only vmem wait.
// Loads made wave-count-uniform (dummy 13th granule / dummy TW lane) so the
// compiler's static vmcnt counting stays exact.
__launch_bounds__(512, 2)
__global__ void attn_main(const float* __restrict__ hist,
                          const float* __restrict__ TW,
                          const float* __restrict__ q,
                          const short* __restrict__ wfrag,
                          float* __restrict__ out) {
    __shared__ __align__(16) uint2 h2[2][T_PAD * 32];  // 2 x 53248 B bf16 tiles
    __shared__ float s_tw[2][D_EMB];
    __shared__ float s_logits[2][T_PAD];
    __shared__ float s_scores[T_PAD];
    __shared__ float s_red[16];
    __shared__ float s_p2[16][D_EMB];

    const int tid = threadIdx.x;
    const int l = tid & 63;
    const int w = tid >> 6;
    const int p = w & 3;
    const int hf = w >> 2;
    const int l15 = l & 15;
    const int lg = l >> 4;
    const int r = tid >> 5;
    const int cc = tid & 31;
    const int c_log = (((cc >> 1) ^ (r & 7)) << 1) | (cc & 1);
    const int base_g = r * 32 + c_log;               // + k*512 per k
    const int idx12 = (tid < 256) ? base_g + 12 * 512 : 0;  // uniform 13th load
    const f32x4 vzero = {0.f, 0.f, 0.f, 0.f};

    bf16x8 Bf[4][4];
#pragma unroll
    for (int ks = 0; ks < 4; ++ks)
#pragma unroll
        for (int j = 0; j < 4; ++j)
            Bf[ks][j] = ((const bf16x8*)wfrag)[(ks * 8 + hf * 4 + j) * 64 + l];

    float qv[4];
#pragma unroll
    for (int j = 0; j < 4; ++j) qv[j] = q[hf * 64 + j * 16 + l15];

    // zero pad rows (t=200..207 live at half-granules [6400,6656)) in both buffers
    if (tid >= 256) {
        h2[0][6144 + tid] = uint2{0u, 0u};
        h2[1][6144 + tid] = uint2{0u, 0u};
    }

    const int base = blockIdx.x * ITERS;
    const f32x4* ghist = (const f32x4*)hist;

    f32x4 stgA[13], stgB[13];
    float twA, twB;

    {   // prologue: load tile 0 + issue tile 1 (uniform counts)
        const f32x4* g0 = ghist + (size_t)base * NG;
#pragma unroll
        for (int k = 0; k < 12; ++k) stgA[k] = g0[base_g + k * 512];
        stgA[12] = g0[idx12];
        twA = TW[(size_t)base * D_EMB + (tid & 127)];
        const f32x4* g1 = ghist + (size_t)(base + 1) * NG;
#pragma unroll
        for (int k = 0; k < 12; ++k) stgB[k] = g1[base_g + k * 512];
        stgB[12] = g1[idx12];
        twB = TW[(size_t)(base + 1) * D_EMB + (tid & 127)];
    }
    {   // commit tile 0 -> h2[0]
        uint2* d = h2[0];
#pragma unroll
        for (int k = 0; k < 12; ++k) d[tid + k * 512] = cvt_granule(stgA[k]);
        if (tid < 256) d[tid + 12 * 512] = cvt_granule(stgA[12]);
        if (tid < 128) s_tw[0][tid] = twA;
    }
    wg_barrier();

#define BODY(PAR, STG_CUR, STG_OTH, TW_CUR, TW_OTH, II)                           \
    {                                                                             \
        const int bb = base + (II);                                               \
        float twv[4];                                                             \
        _Pragma("unroll") for (int j = 0; j < 4; ++j)                             \
            twv[j] = s_tw[PAR][hf * 64 + j * 16 + l15];                           \
        const bf16x8* hp = (const bf16x8*)h2[PAR];                                \
        for (int mt = p; mt < 13; mt += 4) {                                      \
            f32x4 acc[4];                                                         \
            _Pragma("unroll") for (int j = 0; j < 4; ++j) acc[j] = vzero;         \
            _Pragma("unroll") for (int ks = 0; ks < 4; ++ks) {                    \
                bf16x8 A = hp[l15 * 16 + ((ks * 4 + lg) ^ (l15 & 7)) + mt * 256]; \
                _Pragma("unroll") for (int j = 0; j < 4; ++j)                     \
                    acc[j] = __builtin_amdgcn_mfma_f32_16x16x32_bf16(             \
                        A, Bf[ks][j], acc[j], 0, 0, 0);                           \
            }                                                                     \
            float part[4] = {0.f, 0.f, 0.f, 0.f};                                 \
            _Pragma("unroll") for (int j = 0; j < 4; ++j) {                       \
                _Pragma("unroll") for (int rr = 0; rr < 4; ++rr)                  \
                    part[rr] += fmaxf(acc[j][rr] + twv[j], 0.f) * qv[j];          \
            }                                                                     \
            _Pragma("unroll") for (int rr = 0; rr < 4; ++rr)                      \
                part[rr] = dpp_reduce16(part[rr]);                                \
            if (l15 == 0) {                                                       \
                int row = mt * 16 + lg * 4;                                       \
                f32x4 v;                                                          \
                _Pragma("unroll") for (int rr = 0; rr < 4; ++rr)                  \
                    v[rr] = (row + rr < T_HIST) ? part[rr] : -1e30f;              \
                *(f32x4*)&s_logits[hf][row] = v;                                  \
            }                                                                     \
        }                                                                         \
        wg_barrier();                                                             \
        float lv = (tid < T_PAD) ? (s_logits[0][tid] + s_logits[1][tid]) : -1e30f;\
        float m = lv;                                                             \
        _Pragma("unroll") for (int off = 32; off >= 1; off >>= 1)                 \
            m = fmaxf(m, __shfl_xor(m, off, 64));                                 \
        if (l == 0) s_red[w] = m;                                                 \
        wg_barrier();                                                             \
        float M = s_red[0];                                                       \
        _Pragma("unroll") for (int k = 1; k < 8; ++k) M = fmaxf(M, s_red[k]);     \
        float e = (tid < T_PAD) ? __expf(lv - M) : 0.f;                           \
        if (tid < T_PAD) s_scores[tid] = e;                                       \
        float sm = e;                                                             \
        _Pragma("unroll") for (int off = 32; off >= 1; off >>= 1)                 \
            sm += __shfl_xor(sm, off, 64);                                        \
        if (l == 0) s_red[8 + w] = sm;                                            \
        wg_barrier();                                                             \
        float S = s_red[8];                                                       \
        _Pragma("unroll") for (int k = 9; k < 16; ++k) S += s_red[k];             \
        /* pass 2 from exact f32 registers (tile II) */                           \
        f32x4 acc2 = vzero;                                                       \
        _Pragma("unroll") for (int k = 0; k < 12; ++k) {                          \
            float sc = s_scores[r + 16 * k];                                      \
            _Pragma("unroll") for (int rr = 0; rr < 4; ++rr)                      \
                acc2[rr] = fmaf(sc, STG_CUR[k][rr], acc2[rr]);                    \
        }                                                                         \
        if (tid < 256) {                                                          \
            float sc = s_scores[r + 192];                                         \
            _Pragma("unroll") for (int rr = 0; rr < 4; ++rr)                      \
                acc2[rr] = fmaf(sc, STG_CUR[12][rr], acc2[rr]);                   \
        }                                                                         \
        *(f32x4*)&s_p2[r][c_log * 4] = acc2;                                      \
        wg_barrier();                                                             \
        if (tid < 128) {                                                          \
            float o = 0.f;                                                        \
            _Pragma("unroll") for (int k = 0; k < 16; ++k) o += s_p2[k][tid];     \
            out[(size_t)bb * D_EMB + tid] = o / S;                                \
        }                                                                         \
        /* issue loads for tile II+2 into the just-freed STG_CUR (uniform) */     \
        if ((II) + 2 < ITERS) {                                                   \
            const f32x4* gn = ghist + (size_t)(bb + 2) * NG;                      \
            _Pragma("unroll") for (int k = 0; k < 12; ++k)                        \
                STG_CUR[k] = gn[base_g + k * 512];                                \
            STG_CUR[12] = gn[idx12];                                              \
            TW_CUR = TW[(size_t)(bb + 2) * D_EMB + (tid & 127)];                  \
        }                                                                         \
        /* commit tile II+1 (loads issued a full body ago; compiler emits */      \
        /* counted vmcnt for these register deps - no full drain) */              \
        if ((II) + 1 < ITERS) {                                                   \
            uint2* d = h2[1 - (PAR)];                                             \
            _Pragma("unroll") for (int k = 0; k < 12; ++k)                        \
                d[tid + k * 512] = cvt_granule(STG_OTH[k]);                       \
            if (tid < 256) d[tid + 12 * 512] = cvt_granule(STG_OTH[12]);          \
            if (tid < 128) s_tw[1 - (PAR)][tid] = TW_OTH;                         \
        }                                                                         \
        wg_barrier();                                                             \
    }

    for (int ii = 0; ii < ITERS; ii += 2) {
        BODY(0, stgA, stgB, twA, twB, ii)
        BODY(1, stgB, stgA, twB, twA, ii + 1)
    }
#undef BODY
}

extern "C" void kernel_launch(void* const* d_in, const int* in_sizes, int n_in,
                              void* d_out, int out_size, void* d_ws, size_t ws_size,
                              hipStream_t stream) {
    const float* target = (const float*)d_in[0];
    const float* hist   = (const float*)d_in[1];
    const float* Wk     = (const float*)d_in[2];
    const float* Wb     = (const float*)d_in[3];
    const float* qk     = (const float*)d_in[4];
    float* out = (float*)d_out;

    short* wfrag = (short*)d_ws;                   // 32 KB
    float* TW    = (float*)((char*)d_ws + 32768);  // 8 MB

    pack_w_kernel<<<dim3(8), dim3(256), 0, stream>>>(Wk, wfrag);
    tw_kernel<<<dim3(2048), dim3(128), 0, stream>>>(target, Wk, Wb, TW);
    attn_main<<<dim3(NBLK), dim3(512), 0, stream>>>(hist, TW, qk, wfrag, out);
}

// Round 9
// 387.204 us; speedup vs baseline: 1.1564x; 1.1564x over previous
//
#include <hip/hip_runtime.h>
#include <hip/hip_bf16.h>

#define D_EMB 128
#define T_HIST 200
#define T_PAD 208
#define NG 6400      // f32x4 granules per batch row
#define ITERS 32
#define NBLK 512     // 2 blocks per CU

typedef float f32x4 __attribute__((ext_vector_type(4)));
typedef short bf16x8 __attribute__((ext_vector_type(8)));

__device__ __forceinline__ short f2bf(float f) {
    unsigned u = __builtin_bit_cast(unsigned, f);
    u += 0x7fffu + ((u >> 16) & 1u);
    return (short)(u >> 16);
}

// proven DPP 16-lane-group sum
__device__ __forceinline__ float dpp_reduce16(float x) {
    int v = __builtin_bit_cast(int, x);
    x += __builtin_bit_cast(float, __builtin_amdgcn_update_dpp(0, v, 0xB1, 0xF, 0xF, true));
    v = __builtin_bit_cast(int, x);
    x += __builtin_bit_cast(float, __builtin_amdgcn_update_dpp(0, v, 0x4E, 0xF, 0xF, true));
    v = __builtin_bit_cast(int, x);
    x += __builtin_bit_cast(float, __builtin_amdgcn_update_dpp(0, v, 0x141, 0xF, 0xF, true));
    v = __builtin_bit_cast(int, x);
    x += __builtin_bit_cast(float, __builtin_amdgcn_update_dpp(0, v, 0x140, 0xF, 0xF, true));
    return x;
}

// f32x4 granule -> 4 packed RNE bf16 (8B)
__device__ __forceinline__ uint2 cvt_granule(f32x4 v) {
    uint2 r;
    asm("v_cvt_pk_bf16_f32 %0, %1, %2" : "=v"(r.x) : "v"(v[0]), "v"(v[1]));
    asm("v_cvt_pk_bf16_f32 %0, %1, %2" : "=v"(r.y) : "v"(v[2]), "v"(v[3]));
    return r;
}

__global__ void pack_w_kernel(const float* __restrict__ W, short* __restrict__ wfrag) {
    int tid = blockIdx.x * blockDim.x + threadIdx.x;
    int fragid = tid >> 6;
    int lane = tid & 63;
    int ks = fragid >> 3;
    int nt = fragid & 7;
    int n = nt * 16 + (lane & 15);
    int k0 = ks * 32 + (lane >> 4) * 8;
    bf16x8 r;
#pragma unroll
    for (int j = 0; j < 8; ++j) r[j] = f2bf(W[(k0 + j) * D_EMB + n]);
    ((bf16x8*)wfrag)[fragid * 64 + lane] = r;
}

__global__ void tw_kernel(const float* __restrict__ target, const float* __restrict__ W,
                          const float* __restrict__ bias, float* __restrict__ TW) {
    int e = threadIdx.x;
    int b0 = blockIdx.x * 8;
    float bv = bias[e];
    float acc[8];
#pragma unroll
    for (int i = 0; i < 8; ++i) acc[i] = bv;
    for (int d = 0; d < D_EMB; ++d) {
        float wv = W[d * D_EMB + e];
#pragma unroll
        for (int i = 0; i < 8; ++i)
            acc[i] = fmaf(target[(size_t)(b0 + i) * D_EMB + d], wv, acc[i]);
    }
#pragma unroll
    for (int i = 0; i < 8; ++i) TW[(size_t)(b0 + i) * D_EMB + e] = acc[i];
}

// TLP version: 512 blocks (2/CU), single-buffered bf16 LDS tile (53 KB),
// plain __syncthreads (the sibling block hides barrier/vmcnt stalls).
// Wave w owns n-tile w (16 cols): Bf[4] = 16 VGPR. Logit partials summed
// across 8 waves via s_logits[8][T]. Data path (gather/swizzle, commit,
// MFMA A pointer-cast read, exact-f32 pass2 from regs) is verbatim R6.
__launch_bounds__(512, 4)
__global__ void attn_main(const float* __restrict__ hist,
                          const float* __restrict__ TW,
                          const float* __restrict__ q,
                          const short* __restrict__ wfrag,
                          float* __restrict__ out) {
    __shared__ __align__(16) uint2 h2[T_PAD * 32];  // 53248 B bf16 tile
    __shared__ float s_tw[D_EMB];                   // 512 B
    __shared__ float s_logits[8][T_PAD];            // 6656 B
    __shared__ float s_scores[T_PAD];               // 832 B
    __shared__ float s_red[16];                     // 64 B
    __shared__ float s_p2[16][D_EMB];               // 8192 B

    const int tid = threadIdx.x;
    const int l = tid & 63;
    const int w = tid >> 6;   // wave id == n-tile id (cols w*16..w*16+15)
    const int l15 = l & 15;
    const int lg = l >> 4;
    const int r = tid >> 5;
    const int cc = tid & 31;
    const int c_log = (((cc >> 1) ^ (r & 7)) << 1) | (cc & 1);
    const int base_g = r * 32 + c_log;  // + k*512 per k
    const f32x4 vzero = {0.f, 0.f, 0.f, 0.f};

    // resident B fragments for this wave's n-tile: 4 x 4 VGPR = 16
    bf16x8 Bf[4];
#pragma unroll
    for (int ks = 0; ks < 4; ++ks)
        Bf[ks] = ((const bf16x8*)wfrag)[(ks * 8 + w) * 64 + l];

    const float qv = q[w * 16 + l15];

    // zero pad rows t=200..207 (8B units [6400,6656)) once
    if (tid >= 256) h2[6144 + tid] = uint2{0u, 0u};

    const int base = blockIdx.x * ITERS;
    const f32x4* ghist = (const f32x4*)hist;

    f32x4 stg[13];
    float twstg = 0.f;

    {   // prologue: load tile 0
        const f32x4* g0 = ghist + (size_t)base * NG;
#pragma unroll
        for (int k = 0; k < 12; ++k) stg[k] = g0[base_g + k * 512];
        if (tid < 256) stg[12] = g0[base_g + 12 * 512];
        if (tid < 128) twstg = TW[(size_t)base * D_EMB + tid];
    }

    for (int i = 0; i < ITERS; ++i) {
        const int b = base + i;

        // ---- commit staged tile (cvt f32->bf16), waits vmcnt naturally ----
#pragma unroll
        for (int k = 0; k < 12; ++k) h2[tid + k * 512] = cvt_granule(stg[k]);
        if (tid < 256) h2[tid + 12 * 512] = cvt_granule(stg[12]);
        if (tid < 128) s_tw[tid] = twstg;
        __syncthreads();  // B1

        // ---- MFMA: all 13 m-tiles for this wave's 16 columns ----
        const float twv = s_tw[w * 16 + l15];
        const bf16x8* hp = (const bf16x8*)h2;
        for (int mt = 0; mt < 13; ++mt) {
            f32x4 acc = vzero;
#pragma unroll
            for (int ks = 0; ks < 4; ++ks) {
                bf16x8 A = hp[l15 * 16 + ((ks * 4 + lg) ^ (l15 & 7)) + mt * 256];
                acc = __builtin_amdgcn_mfma_f32_16x16x32_bf16(A, Bf[ks], acc, 0, 0, 0);
            }
            // C/D: row = lg*4 + rr, col = l15 (within n-tile w)
            float part[4];
#pragma unroll
            for (int rr = 0; rr < 4; ++rr)
                part[rr] = fmaxf(acc[rr] + twv, 0.f) * qv;
#pragma unroll
            for (int rr = 0; rr < 4; ++rr) part[rr] = dpp_reduce16(part[rr]);
            if (l15 == 0) {
                int row = mt * 16 + lg * 4;
                f32x4 v;
#pragma unroll
                for (int rr = 0; rr < 4; ++rr)
                    v[rr] = (row + rr < T_HIST) ? part[rr] : -1e30f;
                *(f32x4*)&s_logits[w][row] = v;
            }
        }
        __syncthreads();  // B2

        // ---- softmax over T: sum the 8 per-wave partials ----
        float lv = -1e30f;
        if (tid < T_PAD) {
            lv = s_logits[0][tid] + s_logits[1][tid] + s_logits[2][tid] + s_logits[3][tid]
               + s_logits[4][tid] + s_logits[5][tid] + s_logits[6][tid] + s_logits[7][tid];
        }
        float m = lv;
#pragma unroll
        for (int off = 32; off >= 1; off >>= 1)
            m = fmaxf(m, __shfl_xor(m, off, 64));
        if (l == 0) s_red[w] = m;
        __syncthreads();  // B3
        float M = s_red[0];
#pragma unroll
        for (int k = 1; k < 8; ++k) M = fmaxf(M, s_red[k]);
        float e = (tid < T_PAD) ? __expf(lv - M) : 0.f;
        if (tid < T_PAD) s_scores[tid] = e;
        float sm = e;
#pragma unroll
        for (int off = 32; off >= 1; off >>= 1)
            sm += __shfl_xor(sm, off, 64);
        if (l == 0) s_red[8 + w] = sm;
        __syncthreads();  // B4
        float S = s_red[8];
#pragma unroll
        for (int k = 9; k < 16; ++k) S += s_red[k];

        // ---- pass 2 from exact f32 registers ----
        f32x4 acc2 = vzero;
#pragma unroll
        for (int k = 0; k < 12; ++k) {
            float sc = s_scores[r + 16 * k];
#pragma unroll
            for (int rr = 0; rr < 4; ++rr)
                acc2[rr] = fmaf(sc, stg[k][rr], acc2[rr]);
        }
        if (tid < 256) {
            float sc = s_scores[r + 192];
#pragma unroll
            for (int rr = 0; rr < 4; ++rr)
                acc2[rr] = fmaf(sc, stg[12][rr], acc2[rr]);
        }
        *(f32x4*)&s_p2[r][c_log * 4] = acc2;
        __syncthreads();  // B5
        if (tid < 128) {
            float o = 0.f;
#pragma unroll
            for (int k = 0; k < 16; ++k) o += s_p2[k][tid];
            out[(size_t)b * D_EMB + tid] = o / S;
        }

        // ---- issue next tile's loads (commit at loop top consumes them) ----
        if (i + 1 < ITERS) {
            const f32x4* gn = ghist + (size_t)(b + 1) * NG;
#pragma unroll
            for (int k = 0; k < 12; ++k) stg[k] = gn[base_g + k * 512];
            if (tid < 256) stg[12] = gn[base_g + 12 * 512];
            if (tid < 128) twstg = TW[(size_t)(b + 1) * D_EMB + tid];
        }
    }
}

extern "C" void kernel_launch(void* const* d_in, const int* in_sizes, int n_in,
                              void* d_out, int out_size, void* d_ws, size_t ws_size,
                              hipStream_t stream) {
    const float* target = (const float*)d_in[0];
    const float* hist   = (const float*)d_in[1];
    const float* Wk     = (const float*)d_in[2];
    const float* Wb     = (const float*)d_in[3];
    const float* qk     = (const float*)d_in[4];
    float* out = (float*)d_out;

    short* wfrag = (short*)d_ws;                   // 32 KB
    float* TW    = (float*)((char*)d_ws + 32768);  // 8 MB

    pack_w_kernel<<<dim3(8), dim3(256), 0, stream>>>(Wk, wfrag);
    tw_kernel<<<dim3(2048), dim3(128), 0, stream>>>(target, Wk, Wb, TW);
    attn_main<<<dim3(NBLK), dim3(512), 0, stream>>>(hist, TW, qk, wfrag, out);
}

// Round 10
// 365.955 us; speedup vs baseline: 1.2235x; 1.0581x over previous
//
#include <hip/hip_runtime.h>
#include <hip/hip_bf16.h>

#define D_EMB 128
#define T_HIST 200
#define T_PAD 208
#define NG 6400      // f32x4 granules per batch row
#define ITERS 64
#define NBLK 256

typedef float f32x4 __attribute__((ext_vector_type(4)));
typedef short bf16x8 __attribute__((ext_vector_type(8)));

__device__ __forceinline__ short f2bf(float f) {
    unsigned u = __builtin_bit_cast(unsigned, f);
    u += 0x7fffu + ((u >> 16) & 1u);
    return (short)(u >> 16);
}

// Barrier that publishes LDS (lgkmcnt(0)) but does NOT drain in-flight global
// register loads (unlike __syncthreads' implicit vmcnt(0)). No sched_barrier:
// A-fragment LDS reads are compiler-visible loads, so their reg-dep waits are
// auto-counted; the "memory" clobber pins LDS op ordering around the barrier.
__device__ __forceinline__ void wg_barrier() {
    asm volatile("s_waitcnt lgkmcnt(0)" ::: "memory");
    __builtin_amdgcn_s_barrier();
}

// proven DPP 16-lane-group sum (rounds 2 vs 3 bit-identical vs shfl)
__device__ __forceinline__ float dpp_reduce16(float x) {
    int v = __builtin_bit_cast(int, x);
    x += __builtin_bit_cast(float, __builtin_amdgcn_update_dpp(0, v, 0xB1, 0xF, 0xF, true));
    v = __builtin_bit_cast(int, x);
    x += __builtin_bit_cast(float, __builtin_amdgcn_update_dpp(0, v, 0x4E, 0xF, 0xF, true));
    v = __builtin_bit_cast(int, x);
    x += __builtin_bit_cast(float, __builtin_amdgcn_update_dpp(0, v, 0x141, 0xF, 0xF, true));
    v = __builtin_bit_cast(int, x);
    x += __builtin_bit_cast(float, __builtin_amdgcn_update_dpp(0, v, 0x140, 0xF, 0xF, true));
    return x;
}

// f32x4 granule -> 4 packed RNE bf16 (8B), via HW packed convert
__device__ __forceinline__ uint2 cvt_granule(f32x4 v) {
    uint2 r;
    asm("v_cvt_pk_bf16_f32 %0, %1, %2" : "=v"(r.x) : "v"(v[0]), "v"(v[1]));
    asm("v_cvt_pk_bf16_f32 %0, %1, %2" : "=v"(r.y) : "v"(v[2]), "v"(v[3]));
    return r;
}

__global__ void pack_w_kernel(const float* __restrict__ W, short* __restrict__ wfrag) {
    int tid = blockIdx.x * blockDim.x + threadIdx.x;
    int fragid = tid >> 6;
    int lane = tid & 63;
    int ks = fragid >> 3;
    int nt = fragid & 7;
    int n = nt * 16 + (lane & 15);
    int k0 = ks * 32 + (lane >> 4) * 8;
    bf16x8 r;
#pragma unroll
    for (int j = 0; j < 8; ++j) r[j] = f2bf(W[(k0 + j) * D_EMB + n]);
    ((bf16x8*)wfrag)[fragid * 64 + lane] = r;
}

__global__ void tw_kernel(const float* __restrict__ target, const float* __restrict__ W,
                          const float* __restrict__ bias, float* __restrict__ TW) {
    int e = threadIdx.x;
    int b0 = blockIdx.x * 8;
    float bv = bias[e];
    float acc[8];
#pragma unroll
    for (int i = 0; i < 8; ++i) acc[i] = bv;
    for (int d = 0; d < D_EMB; ++d) {
        float wv = W[d * D_EMB + e];
#pragma unroll
        for (int i = 0; i < 8; ++i)
            acc[i] = fmaf(target[(size_t)(b0 + i) * D_EMB + d], wv, acc[i]);
    }
#pragma unroll
    for (int i = 0; i < 8; ++i) TW[(size_t)(b0 + i) * D_EMB + e] = acc[i];
}

// R6 (366us, proven) byte-for-byte, with ONE delta: __syncthreads ->
// wg_barrier (lgkmcnt(0)+s_barrier, no vmcnt drain). The prefetch issued at
// body end now stays in flight across all of body i+1's barriers until the
// commit's compiler-counted register-dep vmcnt consumes it (~full-body
// runway ~5us > 4.7us HBM latency+service) -> commit stall ~0.
__launch_bounds__(512, 2)
__global__ void attn_main(const float* __restrict__ hist,
                          const float* __restrict__ TW,
                          const float* __restrict__ q,
                          const short* __restrict__ wfrag,
                          float* __restrict__ out) {
    __shared__ __align__(16) uint2 h2[2][T_PAD * 32];  // 2 x 53248 B bf16 tiles
    __shared__ float s_tw[2][D_EMB];
    __shared__ float s_logits[2][T_PAD];
    __shared__ float s_scores[T_PAD];
    __shared__ float s_red[16];
    __shared__ float s_p2[16][D_EMB];

    const int tid = threadIdx.x;
    const int l = tid & 63;
    const int w = tid >> 6;
    const int p = w & 3;
    const int hf = w >> 2;
    const int l15 = l & 15;
    const int lg = l >> 4;
    const int r = tid >> 5;
    const int cc = tid & 31;
    const int c_log = (((cc >> 1) ^ (r & 7)) << 1) | (cc & 1);
    const int base_g = r * 32 + c_log;  // + k*512 per k
    const f32x4 vzero = {0.f, 0.f, 0.f, 0.f};

    bf16x8 Bf[4][4];
#pragma unroll
    for (int ks = 0; ks < 4; ++ks)
#pragma unroll
        for (int j = 0; j < 4; ++j)
            Bf[ks][j] = ((const bf16x8*)wfrag)[(ks * 8 + hf * 4 + j) * 64 + l];

    float qv[4];
#pragma unroll
    for (int j = 0; j < 4; ++j) qv[j] = q[hf * 64 + j * 16 + l15];

    // zero pad rows (t=200..207 live at half-granules [6400,6656)) in both buffers
    if (tid >= 256) {
        h2[0][6144 + tid] = uint2{0u, 0u};
        h2[1][6144 + tid] = uint2{0u, 0u};
    }

    const int base = blockIdx.x * ITERS;
    const f32x4* ghist = (const f32x4*)hist;

    f32x4 stgA[13], stgB[13];
    float twA = 0.f, twB = 0.f;

    {   // prologue: load tile 0 + issue tile 1
        const f32x4* g0 = ghist + (size_t)base * NG + base_g;
#pragma unroll
        for (int k = 0; k < 12; ++k) stgA[k] = g0[k * 512];
        if (tid < 256) stgA[12] = g0[12 * 512];
        if (tid < 128) twA = TW[(size_t)base * D_EMB + tid];
        const f32x4* g1 = ghist + (size_t)(base + 1) * NG + base_g;
#pragma unroll
        for (int k = 0; k < 12; ++k) stgB[k] = g1[k * 512];
        if (tid < 256) stgB[12] = g1[12 * 512];
        if (tid < 128) twB = TW[(size_t)(base + 1) * D_EMB + tid];
    }
    {   // commit tile 0 -> h2[0]
        uint2* d = h2[0];
#pragma unroll
        for (int k = 0; k < 12; ++k) d[tid + k * 512] = cvt_granule(stgA[k]);
        if (tid < 256) d[tid + 12 * 512] = cvt_granule(stgA[12]);
        if (tid < 128) s_tw[0][tid] = twA;
    }
    wg_barrier();

#define BODY(PAR, STG_CUR, STG_OTH, TW_CUR, TW_OTH, II)                           \
    {                                                                             \
        const int bb = base + (II);                                               \
        float twv[4];                                                             \
        _Pragma("unroll") for (int j = 0; j < 4; ++j)                             \
            twv[j] = s_tw[PAR][hf * 64 + j * 16 + l15];                           \
        const bf16x8* hp = (const bf16x8*)h2[PAR];                                \
        for (int mt = p; mt < 13; mt += 4) {                                      \
            f32x4 acc[4];                                                         \
            _Pragma("unroll") for (int j = 0; j < 4; ++j) acc[j] = vzero;         \
            _Pragma("unroll") for (int ks = 0; ks < 4; ++ks) {                    \
                bf16x8 A = hp[l15 * 16 + ((ks * 4 + lg) ^ (l15 & 7)) + mt * 256]; \
                _Pragma("unroll") for (int j = 0; j < 4; ++j)                     \
                    acc[j] = __builtin_amdgcn_mfma_f32_16x16x32_bf16(             \
                        A, Bf[ks][j], acc[j], 0, 0, 0);                           \
            }                                                                     \
            float part[4] = {0.f, 0.f, 0.f, 0.f};                                 \
            _Pragma("unroll") for (int j = 0; j < 4; ++j) {                       \
                _Pragma("unroll") for (int rr = 0; rr < 4; ++rr)                  \
                    part[rr] += fmaxf(acc[j][rr] + twv[j], 0.f) * qv[j];          \
            }                                                                     \
            _Pragma("unroll") for (int rr = 0; rr < 4; ++rr)                      \
                part[rr] = dpp_reduce16(part[rr]);                                \
            if (l15 == 0) {                                                       \
                int row = mt * 16 + lg * 4;                                       \
                f32x4 v;                                                          \
                _Pragma("unroll") for (int rr = 0; rr < 4; ++rr)                  \
                    v[rr] = (row + rr < T_HIST) ? part[rr] : -1e30f;              \
                *(f32x4*)&s_logits[hf][row] = v;                                  \
            }                                                                     \
        }                                                                         \
        /* commit tile II+1 into the other LDS buffer (compiler-counted vmcnt */  \
        /* on STG_OTH reg deps; loads issued at end of body II-1) */              \
        if ((II) + 1 < ITERS) {                                                   \
            uint2* d = h2[1 - (PAR)];                                             \
            _Pragma("unroll") for (int k = 0; k < 12; ++k)                        \
                d[tid + k * 512] = cvt_granule(STG_OTH[k]);                       \
            if (tid < 256) d[tid + 12 * 512] = cvt_granule(STG_OTH[12]);          \
            if (tid < 128) s_tw[1 - (PAR)][tid] = TW_OTH;                         \
        }                                                                         \
        wg_barrier();                                                             \
        float lv = (tid < T_PAD) ? (s_logits[0][tid] + s_logits[1][tid]) : -1e30f;\
        float m = lv;                                                             \
        _Pragma("unroll") for (int off = 32; off >= 1; off >>= 1)                 \
            m = fmaxf(m, __shfl_xor(m, off, 64));                                 \
        if (l == 0) s_red[w] = m;                                                 \
        wg_barrier();                                                             \
        float M = s_red[0];                                                       \
        _Pragma("unroll") for (int k = 1; k < 8; ++k) M = fmaxf(M, s_red[k]);     \
        float e = (tid < T_PAD) ? __expf(lv - M) : 0.f;                           \
        if (tid < T_PAD) s_scores[tid] = e;                                       \
        float sm = e;                                                             \
        _Pragma("unroll") for (int off = 32; off >= 1; off >>= 1)                 \
            sm += __shfl_xor(sm, off, 64);                                        \
        if (l == 0) s_red[8 + w] = sm;                                            \
        wg_barrier();                                                             \
        float S = s_red[8];                                                       \
        _Pragma("unroll") for (int k = 9; k < 16; ++k) S += s_red[k];             \
        /* pass 2 from exact f32 registers (tile II) */                           \
        f32x4 acc2 = vzero;                                                       \
        _Pragma("unroll") for (int k = 0; k < 12; ++k) {                          \
            float sc = s_scores[r + 16 * k];                                      \
            _Pragma("unroll") for (int rr = 0; rr < 4; ++rr)                      \
                acc2[rr] = fmaf(sc, STG_CUR[k][rr], acc2[rr]);                    \
        }                                                                         \
        if (tid < 256) {                                                          \
            float sc = s_scores[r + 192];                                         \
            _Pragma("unroll") for (int rr = 0; rr < 4; ++rr)                      \
                acc2[rr] = fmaf(sc, STG_CUR[12][rr], acc2[rr]);                   \
        }                                                                         \
        *(f32x4*)&s_p2[r][c_log * 4] = acc2;                                      \
        wg_barrier();                                                             \
        if (tid < 128) {                                                          \
            float o = 0.f;                                                        \
            _Pragma("unroll") for (int k = 0; k < 16; ++k) o += s_p2[k][tid];     \
            out[(size_t)bb * D_EMB + tid] = o / S;                                \
        }                                                                         \
        /* issue loads for tile II+2 into the just-freed STG_CUR; they stay */    \
        /* in flight across the next body's barriers until its commit */          \
        if ((II) + 2 < ITERS) {                                                   \
            const f32x4* gn = ghist + (size_t)(bb + 2) * NG + base_g;             \
            _Pragma("unroll") for (int k = 0; k < 12; ++k) STG_CUR[k] = gn[k*512];\
            if (tid < 256) STG_CUR[12] = gn[12 * 512];                            \
            if (tid < 128) TW_CUR = TW[(size_t)(bb + 2) * D_EMB + tid];           \
        }                                                                         \
    }

    for (int ii = 0; ii < ITERS; ii += 2) {
        BODY(0, stgA, stgB, twA, twB, ii)
        BODY(1, stgB, stgA, twB, twA, ii + 1)
    }
#undef BODY
}

extern "C" void kernel_launch(void* const* d_in, const int* in_sizes, int n_in,
                              void* d_out, int out_size, void* d_ws, size_t ws_size,
                              hipStream_t stream) {
    const float* target = (const float*)d_in[0];
    const float* hist   = (const float*)d_in[1];
    const float* Wk     = (const float*)d_in[2];
    const float* Wb     = (const float*)d_in[3];
    const float* qk     = (const float*)d_in[4];
    float* out = (float*)d_out;

    short* wfrag = (short*)d_ws;                   // 32 KB
    float* TW    = (float*)((char*)d_ws + 32768);  // 8 MB

    pack_w_kernel<<<dim3(8), dim3(256), 0, stream>>>(Wk, wfrag);
    tw_kernel<<<dim3(2048), dim3(128), 0, stream>>>(target, Wk, Wb, TW);
    attn_main<<<dim3(NBLK), dim3(512), 0, stream>>>(hist, TW, qk, wfrag, out);
}